// Round 4
// baseline (384.157 us; speedup 1.0000x reference)
//
#include <hip/hip_runtime.h>
#include <cstdint>

typedef unsigned short u16;
typedef __attribute__((ext_vector_type(8))) short short8;
typedef __attribute__((ext_vector_type(4))) float floatx4;

#define BT    8192
#define TSEQ  2048
#define NBAT  4
#define CMOD  512
#define NH    4
#define HD    128
#define DFF   2048
#define CQKV  1536

__device__ __forceinline__ u16 f2bf(float f) {
  union { float f; uint32_t u; } v; v.f = f;
  uint32_t r = v.u + 0x7FFFu + ((v.u >> 16) & 1u);
  return (u16)(r >> 16);
}
__device__ __forceinline__ float bf2f(u16 u) {
  union { uint32_t u; float f; } v; v.u = ((uint32_t)u) << 16; return v.f;
}
__device__ __forceinline__ float exp2a(float x) {
  float r; asm("v_exp_f32 %0, %1" : "=v"(r) : "v"(x)); return r;
}
__device__ __forceinline__ float rcpa(float x) {
  float r; asm("v_rcp_f32 %0, %1" : "=v"(r) : "v"(x)); return r;
}

typedef __attribute__((address_space(1))) const unsigned int ga_u32;
typedef __attribute__((address_space(3))) unsigned int ls_u32;
__device__ __forceinline__ void glds16(const u16* g, u16* l) {
  __builtin_amdgcn_global_load_lds((ga_u32*)g, (ls_u32*)l, 16, 0, 0);
}

// ---------------- fused prep: 4 weight transposes + LN1 (R4-proven) ----------------
__device__ __forceinline__ void tcast_body(const float* __restrict__ W, u16* __restrict__ Wt,
                                           int K, int N, int bx, int by, int tid,
                                           float (*tile)[33]) {
  int n0 = bx * 32, k0 = by * 32;
  int tx = tid & 31, ty = tid >> 5;
  #pragma unroll
  for (int r = 0; r < 32; r += 8)
    tile[r + ty][tx] = W[(size_t)(k0 + r + ty) * N + n0 + tx];
  __syncthreads();
  #pragma unroll
  for (int r = 0; r < 32; r += 8)
    Wt[(size_t)(n0 + r + ty) * K + k0 + tx] = f2bf(tile[tx][r + ty]);
}

__global__ __launch_bounds__(256) void prep_kernel(
    const float* __restrict__ x, const float* __restrict__ g, const float* __restrict__ b,
    const float* __restrict__ wqkv, const float* __restrict__ wproj,
    const float* __restrict__ wff1, const float* __restrict__ wff2,
    u16* __restrict__ ln_out, u16* __restrict__ wqkvT, u16* __restrict__ wprojT,
    u16* __restrict__ wff1T, u16* __restrict__ wff2T) {
  __shared__ float tile[32][33];
  int bid = blockIdx.x, tid = threadIdx.x;
  if (bid < 768) {
    tcast_body(wqkv, wqkvT, CMOD, CQKV, bid % 48, bid / 48, tid, tile);
  } else if (bid < 1024) {
    int id = bid - 768; tcast_body(wproj, wprojT, CMOD, CMOD, id % 16, id / 16, tid, tile);
  } else if (bid < 2048) {
    int id = bid - 1024; tcast_body(wff1, wff1T, CMOD, DFF, id % 64, id / 64, tid, tile);
  } else if (bid < 3072) {
    int id = bid - 2048; tcast_body(wff2, wff2T, DFF, CMOD, id % 16, id / 16, tid, tile);
  } else {
    int row = (bid - 3072) * 4 + (tid >> 6);
    int lane = tid & 63;
    const float4* xr = (const float4*)(x + (size_t)row * CMOD);
    float4 a = xr[lane], c = xr[lane + 64];
    float s = a.x + a.y + a.z + a.w + c.x + c.y + c.z + c.w;
    float q = a.x*a.x + a.y*a.y + a.z*a.z + a.w*a.w
            + c.x*c.x + c.y*c.y + c.z*c.z + c.w*c.w;
    #pragma unroll
    for (int o = 32; o; o >>= 1) { s += __shfl_xor(s, o); q += __shfl_xor(q, o); }
    float mu = s * (1.0f / CMOD);
    float rstd = rsqrtf(q * (1.0f / CMOD) - mu * mu + 1e-5f);
    const float4* gr = (const float4*)g;
    const float4* br = (const float4*)b;
    float4 g0 = gr[lane], g1 = gr[lane + 64], b0 = br[lane], b1 = br[lane + 64];
    u16* orow = ln_out + (size_t)row * CMOD;
    int i0 = lane * 4, i1 = (lane + 64) * 4;
    orow[i0 + 0] = f2bf((a.x - mu) * rstd * g0.x + b0.x);
    orow[i0 + 1] = f2bf((a.y - mu) * rstd * g0.y + b0.y);
    orow[i0 + 2] = f2bf((a.z - mu) * rstd * g0.z + b0.z);
    orow[i0 + 3] = f2bf((a.w - mu) * rstd * g0.w + b0.w);
    orow[i1 + 0] = f2bf((c.x - mu) * rstd * g1.x + b1.x);
    orow[i1 + 1] = f2bf((c.y - mu) * rstd * g1.y + b1.y);
    orow[i1 + 2] = f2bf((c.z - mu) * rstd * g1.z + b1.z);
    orow[i1 + 3] = f2bf((c.w - mu) * rstd * g1.w + b1.w);
  }
}

// ---------------- layernorm (standalone, for LN2; R4-proven) ----------------
__global__ __launch_bounds__(256) void ln_kernel(const float* __restrict__ x,
                                                 const float* __restrict__ g,
                                                 const float* __restrict__ b,
                                                 u16* __restrict__ out) {
  int row = blockIdx.x * 4 + (threadIdx.x >> 6);
  int lane = threadIdx.x & 63;
  const float4* xr = (const float4*)(x + (size_t)row * CMOD);
  float4 a = xr[lane], c = xr[lane + 64];
  float s = a.x + a.y + a.z + a.w + c.x + c.y + c.z + c.w;
  float q = a.x*a.x + a.y*a.y + a.z*a.z + a.w*a.w
          + c.x*c.x + c.y*c.y + c.z*c.z + c.w*c.w;
  #pragma unroll
  for (int o = 32; o; o >>= 1) { s += __shfl_xor(s, o); q += __shfl_xor(q, o); }
  float mu = s * (1.0f / CMOD);
  float rstd = rsqrtf(q * (1.0f / CMOD) - mu * mu + 1e-5f);
  const float4* gr = (const float4*)g;
  const float4* br = (const float4*)b;
  float4 g0 = gr[lane], g1 = gr[lane + 64], b0 = br[lane], b1 = br[lane + 64];
  u16* orow = out + (size_t)row * CMOD;
  int i0 = lane * 4, i1 = (lane + 64) * 4;
  orow[i0 + 0] = f2bf((a.x - mu) * rstd * g0.x + b0.x);
  orow[i0 + 1] = f2bf((a.y - mu) * rstd * g0.y + b0.y);
  orow[i0 + 2] = f2bf((a.z - mu) * rstd * g0.z + b0.z);
  orow[i0 + 3] = f2bf((a.w - mu) * rstd * g0.w + b0.w);
  orow[i1 + 0] = f2bf((c.x - mu) * rstd * g1.x + b1.x);
  orow[i1 + 1] = f2bf((c.y - mu) * rstd * g1.y + b1.y);
  orow[i1 + 2] = f2bf((c.z - mu) * rstd * g1.z + b1.z);
  orow[i1 + 3] = f2bf((c.w - mu) * rstd * g1.w + b1.w);
}

// ---------------- MFMA GEMM: R2 config (frozen) ----------------
template <int EPI, int TM, int TN, int MINW>
__global__ __launch_bounds__(256, MINW) void gemm_kernel(
    const u16* __restrict__ A, const u16* __restrict__ Bt, int K,
    const float* __restrict__ resid, float* __restrict__ outf,
    u16* __restrict__ ob0, u16* __restrict__ ob1, u16* __restrict__ ob2) {
  constexpr int MR  = TM / 32;
  constexpr int NR  = TN / 32;
  constexpr int NAR = TM / 64;
  constexpr int NBR = TN / 64;
  __shared__ __align__(16) u16 As[2][TM * 32];
  __shared__ __align__(16) u16 Bs[2][TN * 32];
  int tid = threadIdx.x;
  int lane = tid & 63, wave = tid >> 6;
  int lane16 = lane & 15, quad = lane >> 4;
  int m0 = blockIdx.y * TM, n0 = blockIdx.x * TN;
  int wm = (wave >> 1) * (TM / 2), wn = (wave & 1) * (TN / 2);

  floatx4 acc[MR][NR];
  #pragma unroll
  for (int i = 0; i < MR; i++)
    #pragma unroll
    for (int j = 0; j < NR; j++) acc[i][j] = (floatx4)(0.0f);

  const u16* agp[NAR]; u16* alp[NAR][2];
  const u16* bgp[NBR]; u16* blp[NBR][2];
  #pragma unroll
  for (int i = 0; i < NAR; i++) {
    int s = i * 256 + tid;
    agp[i] = A + (size_t)(m0 + (s >> 2)) * K + (s & 3) * 8;
    alp[i][0] = &As[0][(i * 256 + wave * 64) * 8];
    alp[i][1] = &As[1][(i * 256 + wave * 64) * 8];
  }
  #pragma unroll
  for (int i = 0; i < NBR; i++) {
    int s = i * 256 + tid;
    bgp[i] = Bt + (size_t)(n0 + (s >> 2)) * K + (s & 3) * 8;
    blp[i][0] = &Bs[0][(i * 256 + wave * 64) * 8];
    blp[i][1] = &Bs[1][(i * 256 + wave * 64) * 8];
  }

  int nk = K >> 5;
  #pragma unroll
  for (int i = 0; i < NAR; i++) glds16(agp[i], alp[i][0]);
  #pragma unroll
  for (int i = 0; i < NBR; i++) glds16(bgp[i], blp[i][0]);

  for (int kt = 0; kt < nk; kt++) {
    __syncthreads();
    int buf = kt & 1;
    if (kt + 1 < nk) {
      int k1 = (kt + 1) * 32;
      #pragma unroll
      for (int i = 0; i < NAR; i++) glds16(agp[i] + k1, alp[i][buf ^ 1]);
      #pragma unroll
      for (int i = 0; i < NBR; i++) glds16(bgp[i] + k1, blp[i][buf ^ 1]);
    }
    short8 af[MR];
    #pragma unroll
    for (int i = 0; i < MR; i++)
      af[i] = *(const short8*)&As[buf][(wm + i * 16 + lane16) * 32 + quad * 8];
    #pragma unroll
    for (int j = 0; j < NR; j++) {
      short8 bfj = *(const short8*)&Bs[buf][(wn + j * 16 + lane16) * 32 + quad * 8];
      #pragma unroll
      for (int i = 0; i < MR; i++)
        acc[i][j] = __builtin_amdgcn_mfma_f32_16x16x32_bf16(af[i], bfj, acc[i][j], 0, 0, 0);
    }
  }

  #pragma unroll
  for (int i = 0; i < MR; i++) {
    #pragma unroll
    for (int j = 0; j < NR; j++) {
      #pragma unroll
      for (int r = 0; r < 4; r++) {
        int m = m0 + wm + i * 16 + quad * 4 + r;
        int n = n0 + wn + j * 16 + lane16;
        float v = acc[i][j][r];
        if (EPI == 0) {
          int bb = m >> 11, t = m & 2047;
          int nn = n & 511, which = n >> 9;
          int h = nn >> 7, d = nn & 127;
          size_t bh = (size_t)(bb * NH + h);
          if (which == 0)      ob0[bh * TSEQ * HD + (size_t)t * HD + d] = f2bf(v * 0.12751743f);
          else if (which == 1) ob1[bh * TSEQ * HD + (size_t)t * HD + d] = f2bf(v);
          else                 ob2[bh * HD * TSEQ + (size_t)d * TSEQ + t] = f2bf(v);
        } else if (EPI == 1) {
          size_t idx = (size_t)m * CMOD + n;
          outf[idx] = v + resid[idx];
        } else if (EPI == 2) {
          float ge = 0.5f * v * (1.0f + erff(v * 0.70710678118654752f));
          ob0[(size_t)m * DFF + n] = f2bf(ge);
        } else {
          size_t idx = (size_t)m * CMOD + n;
          outf[idx] = v + resid[idx];
        }
      }
    }
  }
}

// ---------------- flash attention: LDS-free direct-L2 fragments (THE ONLY CHANGE) ----------------
// R3 counters: time/iter ~2000cy vs ~500cy dep chain; MfmaUtil 13%, VALU 47%,
// est. LDS pipe ~46% (16 ds_read + 8 bperm / wave-iter), barrier lockstep + vmcnt(0)
// drain each iter. K/V are L2-resident (512KB/head; FETCH=12MB = cold reads only),
// so LDS staging is pure overhead (guide m169). Now: fragments load straight from
// global (same bytes -> bit-identical): kf = K[kt*32+lane16(+16)][(cc*4+quad)*8],
// vf = V^T[j*16+lane16][kt*32+quad*8]. No __shared__, no __syncthreads, per-wave
// early exit at causal bound, setprio(1) around MFMA clusters (T5 regime: free waves).
__global__ __launch_bounds__(256) void attn_kernel(const u16* __restrict__ qb,
                                                   const u16* __restrict__ kb,
                                                   const u16* __restrict__ vtb,
                                                   u16* __restrict__ po,
                                                   float* __restrict__ pl) {
  int tid = threadIdx.x, wave = tid >> 6, lane = tid & 63;
  int lane16 = lane & 15, quad = lane >> 4;
  int bh = blockIdx.x;
  int cid = 79 - (int)blockIdx.y;  // heavy chunks dispatch first
  int qt, c;
  if (cid < 8)       { qt = cid;                    c = 0; }
  else if (cid < 24) { qt = 8 + ((cid - 8) >> 1);   c = (cid - 8) & 1; }
  else if (cid < 48) { qt = 16 + (cid - 24) / 3;    c = (cid - 24) % 3; }
  else               { qt = 24 + ((cid - 48) >> 2); c = (cid - 48) & 3; }

  int q0w = qt * 64 + wave * 16;
  const u16* Q  = qb  + (size_t)bh * TSEQ * HD;
  const u16* Kg = kb  + (size_t)bh * TSEQ * HD;
  const u16* Vg = vtb + (size_t)bh * HD * TSEQ;

  short8 aq[4];
  {
    int qrow = q0w + lane16;
    #pragma unroll
    for (int cc = 0; cc < 4; cc++)
      aq[cc] = *(const short8*)&Q[(size_t)qrow * HD + cc * 32 + quad * 8];
  }

  int ktw   = (q0w >> 5) + 1;       // causal limit for this wave
  int ktblk = qt * 2 + 2;
  int kt0   = c * 16;
  int kend  = min(min(kt0 + 16, ktblk), ktw);  // per-wave bound; no barrier -> early exit

  floatx4 o[8];
  #pragma unroll
  for (int j = 0; j < 8; j++) o[j] = (floatx4)(0.0f);
  floatx4 ol = (floatx4)(0.0f);

  short8 ones;
  #pragma unroll
  for (int e = 0; e < 8; e++) ones[e] = (short)0x3F80;

  // bpermute source addrs (loop-invariant)
  int addrA = (lane16 + ((quad & 1) << 5)) << 2;
  int addrB = addrA + 64;
  int q_g = q0w + lane16;

  // Direct-fragment base pointers
  const u16* kp0 = Kg + (size_t)(kt0 * 32 + lane16) * HD + quad * 8;
  const u16* kp1 = kp0 + 16 * HD;
  const u16* vp0 = Vg + (size_t)lane16 * TSEQ + kt0 * 32 + quad * 8;

  for (int kt = kt0; kt < kend; kt++) {
    // K fragments: kf0 = K[kt*32+lane16][(cc*4+quad)*8], kf1 = +16 rows
    short8 kf0[4], kf1[4];
    #pragma unroll
    for (int cc = 0; cc < 4; cc++) {
      kf0[cc] = *(const short8*)(kp0 + cc * 32);
      kf1[cc] = *(const short8*)(kp1 + cc * 32);
    }

    floatx4 st0 = (floatx4)(0.0f), st1 = (floatx4)(0.0f);
    __builtin_amdgcn_s_setprio(1);
    #pragma unroll
    for (int cc = 0; cc < 4; cc++) {
      st0 = __builtin_amdgcn_mfma_f32_16x16x32_bf16(kf0[cc], aq[cc], st0, 0, 0, 0);
      st1 = __builtin_amdgcn_mfma_f32_16x16x32_bf16(kf1[cc], aq[cc], st1, 0, 0, 0);
    }
    __builtin_amdgcn_s_setprio(0);

    // V fragments issue here; latency hidden under exp/pack/bpermute
    short8 vf[8];
    #pragma unroll
    for (int j = 0; j < 8; j++)
      vf[j] = *(const short8*)(vp0 + (size_t)(j * 16) * TSEQ);

    int k0b = kt * 32 + quad * 4;
    #pragma unroll
    for (int r = 0; r < 4; r++) {
      float p0 = exp2a(st0[r]);
      float p1 = exp2a(st1[r]);
      if (k0b + r > q_g) p0 = 0.0f;
      if (k0b + r + 16 > q_g) p1 = 0.0f;
      st0[r] = p0; st1[r] = p1;
    }
    uint32_t x0 = __builtin_amdgcn_perm(__float_as_uint(st0[1]), __float_as_uint(st0[0]), 0x07060302u);
    uint32_t x1 = __builtin_amdgcn_perm(__float_as_uint(st0[3]), __float_as_uint(st0[2]), 0x07060302u);
    uint32_t y0 = __builtin_amdgcn_perm(__float_as_uint(st1[1]), __float_as_uint(st1[0]), 0x07060302u);
    uint32_t y1 = __builtin_amdgcn_perm(__float_as_uint(st1[3]), __float_as_uint(st1[2]), 0x07060302u);

    int pAx0 = __builtin_amdgcn_ds_bpermute(addrA, (int)x0);
    int pAx1 = __builtin_amdgcn_ds_bpermute(addrA, (int)x1);
    int pBx0 = __builtin_amdgcn_ds_bpermute(addrB, (int)x0);
    int pBx1 = __builtin_amdgcn_ds_bpermute(addrB, (int)x1);
    int pAy0 = __builtin_amdgcn_ds_bpermute(addrA, (int)y0);
    int pAy1 = __builtin_amdgcn_ds_bpermute(addrA, (int)y1);
    int pBy0 = __builtin_amdgcn_ds_bpermute(addrB, (int)y0);
    int pBy1 = __builtin_amdgcn_ds_bpermute(addrB, (int)y1);

    union { uint32_t u[4]; short8 s; } pf;
    bool hi = quad >= 2;
    pf.u[0] = (uint32_t)(hi ? pAy0 : pAx0);
    pf.u[1] = (uint32_t)(hi ? pAy1 : pAx1);
    pf.u[2] = (uint32_t)(hi ? pBy0 : pBx0);
    pf.u[3] = (uint32_t)(hi ? pBy1 : pBx1);

    __builtin_amdgcn_s_setprio(1);
    #pragma unroll
    for (int j = 0; j < 8; j++)
      o[j] = __builtin_amdgcn_mfma_f32_16x16x32_bf16(pf.s, vf[j], o[j], 0, 0, 0);
    ol = __builtin_amdgcn_mfma_f32_16x16x32_bf16(pf.s, ones, ol, 0, 0, 0);
    __builtin_amdgcn_s_setprio(0);

    kp0 += 32 * HD;
    kp1 += 32 * HD;
    vp0 += 32;
  }

  int slot = (bh * 32 + qt) * 4 + c;
  u16* pob = po + (size_t)slot * 8192;
  #pragma unroll
  for (int r = 0; r < 4; r++) {
    int qr = wave * 16 + quad * 4 + r;
    #pragma unroll
    for (int j = 0; j < 8; j++)
      pob[qr * 128 + j * 16 + lane16] = f2bf(o[j][r]);
    if (lane16 == 0) pl[slot * 64 + qr] = ol[r];
  }
}

// ---------------- reduce: VERBATIM (frozen) ----------------
__global__ __launch_bounds__(256) void reduce_kernel(const u16* __restrict__ po,
                                                     const float* __restrict__ pl,
                                                     u16* __restrict__ attn) {
  int bh = blockIdx.x >> 5, qt = blockIdx.x & 31;
  int tid = threadIdx.x;
  int nch = (2 * qt + 17) >> 4;
  int qrow = tid >> 2;
  int d0 = (tid & 3) * 32;
  float acc[32];
  #pragma unroll
  for (int i = 0; i < 32; i++) acc[i] = 0.0f;
  float l = 0.0f;
  int slot0 = (bh * 32 + qt) * 4;
  for (int c = 0; c < nch; c++) {
    int slot = slot0 + c;
    l += pl[slot * 64 + qrow];
    const short8* p = (const short8*)(po + (size_t)slot * 8192 + qrow * 128 + d0);
    #pragma unroll
    for (int v = 0; v < 4; v++) {
      short8 pk = p[v];
      #pragma unroll
      for (int e = 0; e < 8; e++) acc[v * 8 + e] += bf2f((u16)pk[e]);
    }
  }
  float inv = rcpa(l);
  int b = bh >> 2, h = bh & 3, t = qt * 64 + qrow;
  u16* orow = attn + ((size_t)(b * TSEQ + t)) * CMOD + h * HD + d0;
  #pragma unroll
  for (int v = 0; v < 4; v++) {
    short8 ov;
    #pragma unroll
    for (int e = 0; e < 8; e++) ov[e] = (short)f2bf(acc[v * 8 + e] * inv);
    *(short8*)(orow + v * 8) = ov;
  }
}

extern "C" void kernel_launch(void* const* d_in, const int* in_sizes, int n_in,
                              void* d_out, int out_size, void* d_ws, size_t ws_size,
                              hipStream_t stream) {
  const float* x     = (const float*)d_in[0];
  const float* ln1g  = (const float*)d_in[1];
  const float* ln1b  = (const float*)d_in[2];
  const float* wqkv  = (const float*)d_in[3];
  const float* wproj = (const float*)d_in[4];
  const float* ln2g  = (const float*)d_in[5];
  const float* ln2b  = (const float*)d_in[6];
  const float* wff1  = (const float*)d_in[7];
  const float* wff2  = (const float*)d_in[8];
  float* out = (float*)d_out;
  char* ws = (char*)d_ws;

  u16* wt_qkv  = (u16*)(ws);
  u16* wt_proj = (u16*)(ws + 1572864);
  u16* wt_ff1  = (u16*)(ws + 2097152);
  u16* wt_ff2  = (u16*)(ws + 4194304);
  u16* ln_buf  = (u16*)(ws + 6291456);
  u16* q_buf   = (u16*)(ws + 14680064);
  u16* k_buf   = (u16*)(ws + 23068672);
  u16* vt_buf  = (u16*)(ws + 31457280);
  u16* attn    = (u16*)(ws + 39845888);
  float* x2    = (float*)(ws + 48234496);
  u16* h1      = (u16*)(ws + 65011712);
  u16* po      = (u16*)(ws + 48234496);
  float* pl    = (float*)(ws + 81788928);

  dim3 blk(256);
  prep_kernel<<<dim3(5120), blk, 0, stream>>>(x, ln1g, ln1b, wqkv, wproj, wff1, wff2,
                                              ln_buf, wt_qkv, wt_proj, wt_ff1, wt_ff2);

  // QKV: 128x64 tiles, grid 24x64 = 1536 blocks (6/CU)
  gemm_kernel<0, 128, 64, 6><<<dim3(CQKV / 64, BT / 128), blk, 0, stream>>>(
      ln_buf, wt_qkv, CMOD, nullptr, nullptr, q_buf, k_buf, vt_buf);

  attn_kernel<<<dim3(NBAT * NH, 80), blk, 0, stream>>>(q_buf, k_buf, vt_buf, po, pl);

  reduce_kernel<<<dim3(512), blk, 0, stream>>>(po, pl, attn);

  // proj: 64x64 tiles, grid 8x128 = 1024 blocks (4/CU)
  gemm_kernel<1, 64, 64, 4><<<dim3(CMOD / 64, BT / 64), blk, 0, stream>>>(
      attn, wt_proj, CMOD, x, x2, nullptr, nullptr, nullptr);

  ln_kernel<<<dim3(BT / 4), blk, 0, stream>>>(x2, ln2g, ln2b, ln_buf);

  // FF1: 128x64 tiles, grid 32x64 = 2048 blocks
  gemm_kernel<2, 128, 64, 6><<<dim3(DFF / 64, BT / 128), blk, 0, stream>>>(
      ln_buf, wt_ff1, CMOD, nullptr, nullptr, h1, nullptr, nullptr);

  // FF2: 64x64 tiles, grid 8x128 = 1024 blocks
  gemm_kernel<3, 64, 64, 4><<<dim3(CMOD / 64, BT / 64), blk, 0, stream>>>(
      h1, wt_ff2, DFF, x2, out, nullptr, nullptr, nullptr);
}

// Round 5
// 277.488 us; speedup vs baseline: 1.3844x; 1.3844x over previous
//
#include <hip/hip_runtime.h>
#include <cstdint>

typedef unsigned short u16;
typedef __attribute__((ext_vector_type(8))) short short8;
typedef __attribute__((ext_vector_type(4))) float floatx4;

#define BT    8192
#define TSEQ  2048
#define NBAT  4
#define CMOD  512
#define NH    4
#define HD    128
#define DFF   2048
#define CQKV  1536

__device__ __forceinline__ u16 f2bf(float f) {
  union { float f; uint32_t u; } v; v.f = f;
  uint32_t r = v.u + 0x7FFFu + ((v.u >> 16) & 1u);
  return (u16)(r >> 16);
}
__device__ __forceinline__ float bf2f(u16 u) {
  union { uint32_t u; float f; } v; v.u = ((uint32_t)u) << 16; return v.f;
}
__device__ __forceinline__ float exp2a(float x) {
  float r; asm("v_exp_f32 %0, %1" : "=v"(r) : "v"(x)); return r;
}
__device__ __forceinline__ float rcpa(float x) {
  float r; asm("v_rcp_f32 %0, %1" : "=v"(r) : "v"(x)); return r;
}

typedef __attribute__((address_space(1))) const unsigned int ga_u32;
typedef __attribute__((address_space(3))) unsigned int ls_u32;
__device__ __forceinline__ void glds16(const u16* g, u16* l) {
  __builtin_amdgcn_global_load_lds((ga_u32*)g, (ls_u32*)l, 16, 0, 0);
}

// ---------------- fused prep: 4 weight transposes + LN1 (R4-proven) ----------------
__device__ __forceinline__ void tcast_body(const float* __restrict__ W, u16* __restrict__ Wt,
                                           int K, int N, int bx, int by, int tid,
                                           float (*tile)[33]) {
  int n0 = bx * 32, k0 = by * 32;
  int tx = tid & 31, ty = tid >> 5;
  #pragma unroll
  for (int r = 0; r < 32; r += 8)
    tile[r + ty][tx] = W[(size_t)(k0 + r + ty) * N + n0 + tx];
  __syncthreads();
  #pragma unroll
  for (int r = 0; r < 32; r += 8)
    Wt[(size_t)(n0 + r + ty) * K + k0 + tx] = f2bf(tile[tx][r + ty]);
}

__global__ __launch_bounds__(256) void prep_kernel(
    const float* __restrict__ x, const float* __restrict__ g, const float* __restrict__ b,
    const float* __restrict__ wqkv, const float* __restrict__ wproj,
    const float* __restrict__ wff1, const float* __restrict__ wff2,
    u16* __restrict__ ln_out, u16* __restrict__ wqkvT, u16* __restrict__ wprojT,
    u16* __restrict__ wff1T, u16* __restrict__ wff2T) {
  __shared__ float tile[32][33];
  int bid = blockIdx.x, tid = threadIdx.x;
  if (bid < 768) {
    tcast_body(wqkv, wqkvT, CMOD, CQKV, bid % 48, bid / 48, tid, tile);
  } else if (bid < 1024) {
    int id = bid - 768; tcast_body(wproj, wprojT, CMOD, CMOD, id % 16, id / 16, tid, tile);
  } else if (bid < 2048) {
    int id = bid - 1024; tcast_body(wff1, wff1T, CMOD, DFF, id % 64, id / 64, tid, tile);
  } else if (bid < 3072) {
    int id = bid - 2048; tcast_body(wff2, wff2T, DFF, CMOD, id % 16, id / 16, tid, tile);
  } else {
    int row = (bid - 3072) * 4 + (tid >> 6);
    int lane = tid & 63;
    const float4* xr = (const float4*)(x + (size_t)row * CMOD);
    float4 a = xr[lane], c = xr[lane + 64];
    float s = a.x + a.y + a.z + a.w + c.x + c.y + c.z + c.w;
    float q = a.x*a.x + a.y*a.y + a.z*a.z + a.w*a.w
            + c.x*c.x + c.y*c.y + c.z*c.z + c.w*c.w;
    #pragma unroll
    for (int o = 32; o; o >>= 1) { s += __shfl_xor(s, o); q += __shfl_xor(q, o); }
    float mu = s * (1.0f / CMOD);
    float rstd = rsqrtf(q * (1.0f / CMOD) - mu * mu + 1e-5f);
    const float4* gr = (const float4*)g;
    const float4* br = (const float4*)b;
    float4 g0 = gr[lane], g1 = gr[lane + 64], b0 = br[lane], b1 = br[lane + 64];
    u16* orow = ln_out + (size_t)row * CMOD;
    int i0 = lane * 4, i1 = (lane + 64) * 4;
    orow[i0 + 0] = f2bf((a.x - mu) * rstd * g0.x + b0.x);
    orow[i0 + 1] = f2bf((a.y - mu) * rstd * g0.y + b0.y);
    orow[i0 + 2] = f2bf((a.z - mu) * rstd * g0.z + b0.z);
    orow[i0 + 3] = f2bf((a.w - mu) * rstd * g0.w + b0.w);
    orow[i1 + 0] = f2bf((c.x - mu) * rstd * g1.x + b1.x);
    orow[i1 + 1] = f2bf((c.y - mu) * rstd * g1.y + b1.y);
    orow[i1 + 2] = f2bf((c.z - mu) * rstd * g1.z + b1.z);
    orow[i1 + 3] = f2bf((c.w - mu) * rstd * g1.w + b1.w);
  }
}

// ---------------- layernorm (standalone, for LN2; R4-proven) ----------------
__global__ __launch_bounds__(256) void ln_kernel(const float* __restrict__ x,
                                                 const float* __restrict__ g,
                                                 const float* __restrict__ b,
                                                 u16* __restrict__ out) {
  int row = blockIdx.x * 4 + (threadIdx.x >> 6);
  int lane = threadIdx.x & 63;
  const float4* xr = (const float4*)(x + (size_t)row * CMOD);
  float4 a = xr[lane], c = xr[lane + 64];
  float s = a.x + a.y + a.z + a.w + c.x + c.y + c.z + c.w;
  float q = a.x*a.x + a.y*a.y + a.z*a.z + a.w*a.w
          + c.x*c.x + c.y*c.y + c.z*c.z + c.w*c.w;
  #pragma unroll
  for (int o = 32; o; o >>= 1) { s += __shfl_xor(s, o); q += __shfl_xor(q, o); }
  float mu = s * (1.0f / CMOD);
  float rstd = rsqrtf(q * (1.0f / CMOD) - mu * mu + 1e-5f);
  const float4* gr = (const float4*)g;
  const float4* br = (const float4*)b;
  float4 g0 = gr[lane], g1 = gr[lane + 64], b0 = br[lane], b1 = br[lane + 64];
  u16* orow = out + (size_t)row * CMOD;
  int i0 = lane * 4, i1 = (lane + 64) * 4;
  orow[i0 + 0] = f2bf((a.x - mu) * rstd * g0.x + b0.x);
  orow[i0 + 1] = f2bf((a.y - mu) * rstd * g0.y + b0.y);
  orow[i0 + 2] = f2bf((a.z - mu) * rstd * g0.z + b0.z);
  orow[i0 + 3] = f2bf((a.w - mu) * rstd * g0.w + b0.w);
  orow[i1 + 0] = f2bf((c.x - mu) * rstd * g1.x + b1.x);
  orow[i1 + 1] = f2bf((c.y - mu) * rstd * g1.y + b1.y);
  orow[i1 + 2] = f2bf((c.z - mu) * rstd * g1.z + b1.z);
  orow[i1 + 3] = f2bf((c.w - mu) * rstd * g1.w + b1.w);
}

// ---------------- MFMA GEMM: per-GEMM best-known tile configs ----------------
// QKV/FF1: TM=128,TN=64 (R2-proven: FF1 62.4 -> <57); proj/FF2: TM=128,TN=64
// (R0-proven; R2's TM=64 cost barriers/stores, esp. FF2 at nk=64 with 4 MFMA/iter).
template <int EPI, int TM, int TN, int MINW>
__global__ __launch_bounds__(256, MINW) void gemm_kernel(
    const u16* __restrict__ A, const u16* __restrict__ Bt, int K,
    const float* __restrict__ resid, float* __restrict__ outf,
    u16* __restrict__ ob0, u16* __restrict__ ob1, u16* __restrict__ ob2) {
  constexpr int MR  = TM / 32;
  constexpr int NR  = TN / 32;
  constexpr int NAR = TM / 64;
  constexpr int NBR = TN / 64;
  __shared__ __align__(16) u16 As[2][TM * 32];
  __shared__ __align__(16) u16 Bs[2][TN * 32];
  int tid = threadIdx.x;
  int lane = tid & 63, wave = tid >> 6;
  int lane16 = lane & 15, quad = lane >> 4;
  int m0 = blockIdx.y * TM, n0 = blockIdx.x * TN;
  int wm = (wave >> 1) * (TM / 2), wn = (wave & 1) * (TN / 2);

  floatx4 acc[MR][NR];
  #pragma unroll
  for (int i = 0; i < MR; i++)
    #pragma unroll
    for (int j = 0; j < NR; j++) acc[i][j] = (floatx4)(0.0f);

  const u16* agp[NAR]; u16* alp[NAR][2];
  const u16* bgp[NBR]; u16* blp[NBR][2];
  #pragma unroll
  for (int i = 0; i < NAR; i++) {
    int s = i * 256 + tid;
    agp[i] = A + (size_t)(m0 + (s >> 2)) * K + (s & 3) * 8;
    alp[i][0] = &As[0][(i * 256 + wave * 64) * 8];
    alp[i][1] = &As[1][(i * 256 + wave * 64) * 8];
  }
  #pragma unroll
  for (int i = 0; i < NBR; i++) {
    int s = i * 256 + tid;
    bgp[i] = Bt + (size_t)(n0 + (s >> 2)) * K + (s & 3) * 8;
    blp[i][0] = &Bs[0][(i * 256 + wave * 64) * 8];
    blp[i][1] = &Bs[1][(i * 256 + wave * 64) * 8];
  }

  int nk = K >> 5;
  #pragma unroll
  for (int i = 0; i < NAR; i++) glds16(agp[i], alp[i][0]);
  #pragma unroll
  for (int i = 0; i < NBR; i++) glds16(bgp[i], blp[i][0]);

  for (int kt = 0; kt < nk; kt++) {
    __syncthreads();
    int buf = kt & 1;
    if (kt + 1 < nk) {
      int k1 = (kt + 1) * 32;
      #pragma unroll
      for (int i = 0; i < NAR; i++) glds16(agp[i] + k1, alp[i][buf ^ 1]);
      #pragma unroll
      for (int i = 0; i < NBR; i++) glds16(bgp[i] + k1, blp[i][buf ^ 1]);
    }
    short8 af[MR];
    #pragma unroll
    for (int i = 0; i < MR; i++)
      af[i] = *(const short8*)&As[buf][(wm + i * 16 + lane16) * 32 + quad * 8];
    #pragma unroll
    for (int j = 0; j < NR; j++) {
      short8 bfj = *(const short8*)&Bs[buf][(wn + j * 16 + lane16) * 32 + quad * 8];
      #pragma unroll
      for (int i = 0; i < MR; i++)
        acc[i][j] = __builtin_amdgcn_mfma_f32_16x16x32_bf16(af[i], bfj, acc[i][j], 0, 0, 0);
    }
  }

  #pragma unroll
  for (int i = 0; i < MR; i++) {
    #pragma unroll
    for (int j = 0; j < NR; j++) {
      #pragma unroll
      for (int r = 0; r < 4; r++) {
        int m = m0 + wm + i * 16 + quad * 4 + r;
        int n = n0 + wn + j * 16 + lane16;
        float v = acc[i][j][r];
        if (EPI == 0) {
          int bb = m >> 11, t = m & 2047;
          int nn = n & 511, which = n >> 9;
          int h = nn >> 7, d = nn & 127;
          size_t bh = (size_t)(bb * NH + h);
          if (which == 0)      ob0[bh * TSEQ * HD + (size_t)t * HD + d] = f2bf(v * 0.12751743f);
          else if (which == 1) ob1[bh * TSEQ * HD + (size_t)t * HD + d] = f2bf(v);
          else                 ob2[bh * HD * TSEQ + (size_t)d * TSEQ + t] = f2bf(v);
        } else if (EPI == 1) {
          size_t idx = (size_t)m * CMOD + n;
          outf[idx] = v + resid[idx];
        } else if (EPI == 2) {
          float ge = 0.5f * v * (1.0f + erff(v * 0.70710678118654752f));
          ob0[(size_t)m * DFF + n] = f2bf(ge);
        } else {
          size_t idx = (size_t)m * CMOD + n;
          outf[idx] = v + resid[idx];
        }
      }
    }
  }
}

// ---------------- flash attention: R3 LDS version (proven 57.2) + T5 setprio ----------------
// R4's direct-global fragments reverted: fragment reads are gathers (16B/lane at
// 256B/4KB row stride); LDS staging is what makes the global traffic coalesced.
// Only change vs R3: s_setprio(1) around MFMA clusters (m191 regime: 5 independent
// blocks/CU at different phases).
__global__ __launch_bounds__(256) void attn_kernel(const u16* __restrict__ qb,
                                                   const u16* __restrict__ kb,
                                                   const u16* __restrict__ vtb,
                                                   u16* __restrict__ po,
                                                   float* __restrict__ pl) {
  __shared__ __align__(16) u16 Ks[2][32 * 128];
  __shared__ __align__(16) u16 Vs[2][128 * 32];
  int tid = threadIdx.x, wave = tid >> 6, lane = tid & 63;
  int lane16 = lane & 15, quad = lane >> 4;
  int bh = blockIdx.x;
  int cid = 79 - (int)blockIdx.y;  // heavy chunks dispatch first
  int qt, c;
  if (cid < 8)       { qt = cid;                    c = 0; }
  else if (cid < 24) { qt = 8 + ((cid - 8) >> 1);   c = (cid - 8) & 1; }
  else if (cid < 48) { qt = 16 + (cid - 24) / 3;    c = (cid - 24) % 3; }
  else               { qt = 24 + ((cid - 48) >> 2); c = (cid - 48) & 3; }

  int q0w = qt * 64 + wave * 16;
  const u16* Q  = qb  + (size_t)bh * TSEQ * HD;
  const u16* Kg = kb  + (size_t)bh * TSEQ * HD;
  const u16* Vg = vtb + (size_t)bh * HD * TSEQ;

  short8 aq[4];
  {
    int qrow = q0w + lane16;
    #pragma unroll
    for (int cc = 0; cc < 4; cc++)
      aq[cc] = *(const short8*)&Q[(size_t)qrow * HD + cc * 32 + quad * 8];
  }

  const u16* kgp[2]; const u16* vgp[2];
  u16* klp[2][2]; u16* vlp[2][2];
  #pragma unroll
  for (int i = 0; i < 2; i++) {
    int s = wave * 128 + i * 64 + lane;
    int r = s >> 4, cp = s & 15, cc = cp ^ (r & 7);
    kgp[i] = Kg + (size_t)r * HD + cc * 8;
    int d = s >> 2, cv = (s & 3) ^ ((d >> 1) & 3);
    vgp[i] = Vg + (size_t)d * TSEQ + cv * 8;
    #pragma unroll
    for (int bfr = 0; bfr < 2; bfr++) {
      klp[i][bfr] = &Ks[bfr][(wave * 128 + i * 64) * 8];
      vlp[i][bfr] = &Vs[bfr][(wave * 128 + i * 64) * 8];
    }
  }

  int ktw   = (q0w >> 5) + 1;
  int ktblk = qt * 2 + 2;
  int kt0   = c * 16;
  int kend  = min(kt0 + 16, ktblk);

  floatx4 o[8];
  #pragma unroll
  for (int j = 0; j < 8; j++) o[j] = (floatx4)(0.0f);
  floatx4 ol = (floatx4)(0.0f);

  short8 ones;
  #pragma unroll
  for (int e = 0; e < 8; e++) ones[e] = (short)0x3F80;

  int swl = lane16 & 7;
  int cvr = quad ^ ((lane16 >> 1) & 3);
  int addrA = (lane16 + ((quad & 1) << 5)) << 2;
  int addrB = addrA + 64;
  int q_g = q0w + lane16;

  {
    int ko = kt0 * 32;
    #pragma unroll
    for (int i = 0; i < 2; i++) {
      glds16(kgp[i] + (size_t)ko * HD, klp[i][kt0 & 1]);
      glds16(vgp[i] + ko, vlp[i][kt0 & 1]);
    }
  }

  for (int kt = kt0; kt < kend; kt++) {
    __syncthreads();
    int buf = kt & 1;
    if (kt + 1 < kend) {
      int ko = (kt + 1) * 32;
      #pragma unroll
      for (int i = 0; i < 2; i++) {
        glds16(kgp[i] + (size_t)ko * HD, klp[i][buf ^ 1]);
        glds16(vgp[i] + ko, vlp[i][buf ^ 1]);
      }
    }
    if (kt >= ktw) continue;

    // Swapped QK^T: st[r] = P[q = lane16][k = kt*32 + quad*4 + r (+16 for st1)]
    floatx4 st0 = (floatx4)(0.0f), st1 = (floatx4)(0.0f);
    __builtin_amdgcn_s_setprio(1);
    #pragma unroll
    for (int cc = 0; cc < 4; cc++) {
      short8 kf0 = *(const short8*)&Ks[buf][(lane16 * 16 + ((cc * 4 + quad) ^ swl)) * 8];
      short8 kf1 = *(const short8*)&Ks[buf][((16 + lane16) * 16 + ((cc * 4 + quad) ^ swl)) * 8];
      st0 = __builtin_amdgcn_mfma_f32_16x16x32_bf16(kf0, aq[cc], st0, 0, 0, 0);
      st1 = __builtin_amdgcn_mfma_f32_16x16x32_bf16(kf1, aq[cc], st1, 0, 0, 0);
    }
    __builtin_amdgcn_s_setprio(0);
    short8 vf[8];
    #pragma unroll
    for (int j = 0; j < 8; j++)
      vf[j] = *(const short8*)&Vs[buf][((j * 16 + lane16) * 4 + cvr) * 8];

    int k0b = kt * 32 + quad * 4;
    #pragma unroll
    for (int r = 0; r < 4; r++) {
      float p0 = exp2a(st0[r]);
      float p1 = exp2a(st1[r]);
      if (k0b + r > q_g) p0 = 0.0f;
      if (k0b + r + 16 > q_g) p1 = 0.0f;
      st0[r] = p0; st1[r] = p1;
    }
    uint32_t x0 = __builtin_amdgcn_perm(__float_as_uint(st0[1]), __float_as_uint(st0[0]), 0x07060302u);
    uint32_t x1 = __builtin_amdgcn_perm(__float_as_uint(st0[3]), __float_as_uint(st0[2]), 0x07060302u);
    uint32_t y0 = __builtin_amdgcn_perm(__float_as_uint(st1[1]), __float_as_uint(st1[0]), 0x07060302u);
    uint32_t y1 = __builtin_amdgcn_perm(__float_as_uint(st1[3]), __float_as_uint(st1[2]), 0x07060302u);

    int pAx0 = __builtin_amdgcn_ds_bpermute(addrA, (int)x0);
    int pAx1 = __builtin_amdgcn_ds_bpermute(addrA, (int)x1);
    int pBx0 = __builtin_amdgcn_ds_bpermute(addrB, (int)x0);
    int pBx1 = __builtin_amdgcn_ds_bpermute(addrB, (int)x1);
    int pAy0 = __builtin_amdgcn_ds_bpermute(addrA, (int)y0);
    int pAy1 = __builtin_amdgcn_ds_bpermute(addrA, (int)y1);
    int pBy0 = __builtin_amdgcn_ds_bpermute(addrB, (int)y0);
    int pBy1 = __builtin_amdgcn_ds_bpermute(addrB, (int)y1);

    union { uint32_t u[4]; short8 s; } pf;
    bool hi = quad >= 2;
    pf.u[0] = (uint32_t)(hi ? pAy0 : pAx0);
    pf.u[1] = (uint32_t)(hi ? pAy1 : pAx1);
    pf.u[2] = (uint32_t)(hi ? pBy0 : pBx0);
    pf.u[3] = (uint32_t)(hi ? pBy1 : pBx1);

    __builtin_amdgcn_s_setprio(1);
    #pragma unroll
    for (int j = 0; j < 8; j++)
      o[j] = __builtin_amdgcn_mfma_f32_16x16x32_bf16(pf.s, vf[j], o[j], 0, 0, 0);
    ol = __builtin_amdgcn_mfma_f32_16x16x32_bf16(pf.s, ones, ol, 0, 0, 0);
    __builtin_amdgcn_s_setprio(0);
  }

  int slot = (bh * 32 + qt) * 4 + c;
  u16* pob = po + (size_t)slot * 8192;
  #pragma unroll
  for (int r = 0; r < 4; r++) {
    int qr = wave * 16 + quad * 4 + r;
    #pragma unroll
    for (int j = 0; j < 8; j++)
      pob[qr * 128 + j * 16 + lane16] = f2bf(o[j][r]);
    if (lane16 == 0) pl[slot * 64 + qr] = ol[r];
  }
}

// ---------------- reduce: VERBATIM (frozen) ----------------
__global__ __launch_bounds__(256) void reduce_kernel(const u16* __restrict__ po,
                                                     const float* __restrict__ pl,
                                                     u16* __restrict__ attn) {
  int bh = blockIdx.x >> 5, qt = blockIdx.x & 31;
  int tid = threadIdx.x;
  int nch = (2 * qt + 17) >> 4;
  int qrow = tid >> 2;
  int d0 = (tid & 3) * 32;
  float acc[32];
  #pragma unroll
  for (int i = 0; i < 32; i++) acc[i] = 0.0f;
  float l = 0.0f;
  int slot0 = (bh * 32 + qt) * 4;
  for (int c = 0; c < nch; c++) {
    int slot = slot0 + c;
    l += pl[slot * 64 + qrow];
    const short8* p = (const short8*)(po + (size_t)slot * 8192 + qrow * 128 + d0);
    #pragma unroll
    for (int v = 0; v < 4; v++) {
      short8 pk = p[v];
      #pragma unroll
      for (int e = 0; e < 8; e++) acc[v * 8 + e] += bf2f((u16)pk[e]);
    }
  }
  float inv = rcpa(l);
  int b = bh >> 2, h = bh & 3, t = qt * 64 + qrow;
  u16* orow = attn + ((size_t)(b * TSEQ + t)) * CMOD + h * HD + d0;
  #pragma unroll
  for (int v = 0; v < 4; v++) {
    short8 ov;
    #pragma unroll
    for (int e = 0; e < 8; e++) ov[e] = (short)f2bf(acc[v * 8 + e] * inv);
    *(short8*)(orow + v * 8) = ov;
  }
}

extern "C" void kernel_launch(void* const* d_in, const int* in_sizes, int n_in,
                              void* d_out, int out_size, void* d_ws, size_t ws_size,
                              hipStream_t stream) {
  const float* x     = (const float*)d_in[0];
  const float* ln1g  = (const float*)d_in[1];
  const float* ln1b  = (const float*)d_in[2];
  const float* wqkv  = (const float*)d_in[3];
  const float* wproj = (const float*)d_in[4];
  const float* ln2g  = (const float*)d_in[5];
  const float* ln2b  = (const float*)d_in[6];
  const float* wff1  = (const float*)d_in[7];
  const float* wff2  = (const float*)d_in[8];
  float* out = (float*)d_out;
  char* ws = (char*)d_ws;

  u16* wt_qkv  = (u16*)(ws);
  u16* wt_proj = (u16*)(ws + 1572864);
  u16* wt_ff1  = (u16*)(ws + 2097152);
  u16* wt_ff2  = (u16*)(ws + 4194304);
  u16* ln_buf  = (u16*)(ws + 6291456);
  u16* q_buf   = (u16*)(ws + 14680064);
  u16* k_buf   = (u16*)(ws + 23068672);
  u16* vt_buf  = (u16*)(ws + 31457280);
  u16* attn    = (u16*)(ws + 39845888);
  float* x2    = (float*)(ws + 48234496);
  u16* h1      = (u16*)(ws + 65011712);
  u16* po      = (u16*)(ws + 48234496);
  float* pl    = (float*)(ws + 81788928);

  dim3 blk(256);
  prep_kernel<<<dim3(5120), blk, 0, stream>>>(x, ln1g, ln1b, wqkv, wproj, wff1, wff2,
                                              ln_buf, wt_qkv, wt_proj, wt_ff1, wt_ff2);

  // QKV: TM=128,TN=64, grid 24x64 = 1536 blocks (R2-proven)
  gemm_kernel<0, 128, 64, 6><<<dim3(CQKV / 64, BT / 128), blk, 0, stream>>>(
      ln_buf, wt_qkv, CMOD, nullptr, nullptr, q_buf, k_buf, vt_buf);

  attn_kernel<<<dim3(NBAT * NH, 80), blk, 0, stream>>>(q_buf, k_buf, vt_buf, po, pl);

  reduce_kernel<<<dim3(512), blk, 0, stream>>>(po, pl, attn);

  // proj: TM=128,TN=64, grid 8x64 = 512 blocks (R0-proven)
  gemm_kernel<1, 128, 64, 4><<<dim3(CMOD / 64, BT / 128), blk, 0, stream>>>(
      attn, wt_proj, CMOD, x, x2, nullptr, nullptr, nullptr);

  ln_kernel<<<dim3(BT / 4), blk, 0, stream>>>(x2, ln2g, ln2b, ln_buf);

  // FF1: TM=128,TN=64, grid 32x64 = 2048 blocks (R2-proven)
  gemm_kernel<2, 128, 64, 6><<<dim3(DFF / 64, BT / 128), blk, 0, stream>>>(
      ln_buf, wt_ff1, CMOD, nullptr, nullptr, h1, nullptr, nullptr);

  // FF2: TM=128,TN=64, grid 8x64 = 512 blocks (R0-proven)
  gemm_kernel<3, 128, 64, 4><<<dim3(CMOD / 64, BT / 128), blk, 0, stream>>>(
      h1, wt_ff2, DFF, x2, out, nullptr, nullptr, nullptr);
}

// Round 6
// 271.180 us; speedup vs baseline: 1.4166x; 1.0233x over previous
//
#include <hip/hip_runtime.h>
#include <cstdint>

typedef unsigned short u16;
typedef __attribute__((ext_vector_type(8))) short short8;
typedef __attribute__((ext_vector_type(4))) float floatx4;

#define BT    8192
#define TSEQ  2048
#define NBAT  4
#define CMOD  512
#define NH    4
#define HD    128
#define DFF   2048
#define CQKV  1536

__device__ __forceinline__ u16 f2bf(float f) {
  union { float f; uint32_t u; } v; v.f = f;
  uint32_t r = v.u + 0x7FFFu + ((v.u >> 16) & 1u);
  return (u16)(r >> 16);
}
__device__ __forceinline__ float bf2f(u16 u) {
  union { uint32_t u; float f; } v; v.u = ((uint32_t)u) << 16; return v.f;
}
__device__ __forceinline__ float exp2a(float x) {
  float r; asm("v_exp_f32 %0, %1" : "=v"(r) : "v"(x)); return r;
}
__device__ __forceinline__ float rcpa(float x) {
  float r; asm("v_rcp_f32 %0, %1" : "=v"(r) : "v"(x)); return r;
}

typedef __attribute__((address_space(1))) const unsigned int ga_u32;
typedef __attribute__((address_space(3))) unsigned int ls_u32;
__device__ __forceinline__ void glds16(const u16* g, u16* l) {
  __builtin_amdgcn_global_load_lds((ga_u32*)g, (ls_u32*)l, 16, 0, 0);
}

// ---------------- fused prep: 4 weight transposes + LN1 (frozen) ----------------
__device__ __forceinline__ void tcast_body(const float* __restrict__ W, u16* __restrict__ Wt,
                                           int K, int N, int bx, int by, int tid,
                                           float (*tile)[33]) {
  int n0 = bx * 32, k0 = by * 32;
  int tx = tid & 31, ty = tid >> 5;
  #pragma unroll
  for (int r = 0; r < 32; r += 8)
    tile[r + ty][tx] = W[(size_t)(k0 + r + ty) * N + n0 + tx];
  __syncthreads();
  #pragma unroll
  for (int r = 0; r < 32; r += 8)
    Wt[(size_t)(n0 + r + ty) * K + k0 + tx] = f2bf(tile[tx][r + ty]);
}

__global__ __launch_bounds__(256) void prep_kernel(
    const float* __restrict__ x, const float* __restrict__ g, const float* __restrict__ b,
    const float* __restrict__ wqkv, const float* __restrict__ wproj,
    const float* __restrict__ wff1, const float* __restrict__ wff2,
    u16* __restrict__ ln_out, u16* __restrict__ wqkvT, u16* __restrict__ wprojT,
    u16* __restrict__ wff1T, u16* __restrict__ wff2T) {
  __shared__ float tile[32][33];
  int bid = blockIdx.x, tid = threadIdx.x;
  if (bid < 768) {
    tcast_body(wqkv, wqkvT, CMOD, CQKV, bid % 48, bid / 48, tid, tile);
  } else if (bid < 1024) {
    int id = bid - 768; tcast_body(wproj, wprojT, CMOD, CMOD, id % 16, id / 16, tid, tile);
  } else if (bid < 2048) {
    int id = bid - 1024; tcast_body(wff1, wff1T, CMOD, DFF, id % 64, id / 64, tid, tile);
  } else if (bid < 3072) {
    int id = bid - 2048; tcast_body(wff2, wff2T, DFF, CMOD, id % 16, id / 16, tid, tile);
  } else {
    int row = (bid - 3072) * 4 + (tid >> 6);
    int lane = tid & 63;
    const float4* xr = (const float4*)(x + (size_t)row * CMOD);
    float4 a = xr[lane], c = xr[lane + 64];
    float s = a.x + a.y + a.z + a.w + c.x + c.y + c.z + c.w;
    float q = a.x*a.x + a.y*a.y + a.z*a.z + a.w*a.w
            + c.x*c.x + c.y*c.y + c.z*c.z + c.w*c.w;
    #pragma unroll
    for (int o = 32; o; o >>= 1) { s += __shfl_xor(s, o); q += __shfl_xor(q, o); }
    float mu = s * (1.0f / CMOD);
    float rstd = rsqrtf(q * (1.0f / CMOD) - mu * mu + 1e-5f);
    const float4* gr = (const float4*)g;
    const float4* br = (const float4*)b;
    float4 g0 = gr[lane], g1 = gr[lane + 64], b0 = br[lane], b1 = br[lane + 64];
    u16* orow = ln_out + (size_t)row * CMOD;
    int i0 = lane * 4, i1 = (lane + 64) * 4;
    orow[i0 + 0] = f2bf((a.x - mu) * rstd * g0.x + b0.x);
    orow[i0 + 1] = f2bf((a.y - mu) * rstd * g0.y + b0.y);
    orow[i0 + 2] = f2bf((a.z - mu) * rstd * g0.z + b0.z);
    orow[i0 + 3] = f2bf((a.w - mu) * rstd * g0.w + b0.w);
    orow[i1 + 0] = f2bf((c.x - mu) * rstd * g1.x + b1.x);
    orow[i1 + 1] = f2bf((c.y - mu) * rstd * g1.y + b1.y);
    orow[i1 + 2] = f2bf((c.z - mu) * rstd * g1.z + b1.z);
    orow[i1 + 3] = f2bf((c.w - mu) * rstd * g1.w + b1.w);
  }
}

// ---------------- layernorm (standalone, for LN2; frozen) ----------------
__global__ __launch_bounds__(256) void ln_kernel(const float* __restrict__ x,
                                                 const float* __restrict__ g,
                                                 const float* __restrict__ b,
                                                 u16* __restrict__ out) {
  int row = blockIdx.x * 4 + (threadIdx.x >> 6);
  int lane = threadIdx.x & 63;
  const float4* xr = (const float4*)(x + (size_t)row * CMOD);
  float4 a = xr[lane], c = xr[lane + 64];
  float s = a.x + a.y + a.z + a.w + c.x + c.y + c.z + c.w;
  float q = a.x*a.x + a.y*a.y + a.z*a.z + a.w*a.w
          + c.x*c.x + c.y*c.y + c.z*c.z + c.w*c.w;
  #pragma unroll
  for (int o = 32; o; o >>= 1) { s += __shfl_xor(s, o); q += __shfl_xor(q, o); }
  float mu = s * (1.0f / CMOD);
  float rstd = rsqrtf(q * (1.0f / CMOD) - mu * mu + 1e-5f);
  const float4* gr = (const float4*)g;
  const float4* br = (const float4*)b;
  float4 g0 = gr[lane], g1 = gr[lane + 64], b0 = br[lane], b1 = br[lane + 64];
  u16* orow = out + (size_t)row * CMOD;
  int i0 = lane * 4, i1 = (lane + 64) * 4;
  orow[i0 + 0] = f2bf((a.x - mu) * rstd * g0.x + b0.x);
  orow[i0 + 1] = f2bf((a.y - mu) * rstd * g0.y + b0.y);
  orow[i0 + 2] = f2bf((a.z - mu) * rstd * g0.z + b0.z);
  orow[i0 + 3] = f2bf((a.w - mu) * rstd * g0.w + b0.w);
  orow[i1 + 0] = f2bf((c.x - mu) * rstd * g1.x + b1.x);
  orow[i1 + 1] = f2bf((c.y - mu) * rstd * g1.y + b1.y);
  orow[i1 + 2] = f2bf((c.z - mu) * rstd * g1.z + b1.z);
  orow[i1 + 3] = f2bf((c.w - mu) * rstd * g1.w + b1.w);
}

// ---------------- MFMA GEMM: R5 configs (frozen). ONLY EPI=0 epilogue changed ----------------
// EPI=0 now emits Q/K/V in MFMA-fragment-blocked layouts so attn's fragment reads
// are lane-contiguous (16B/lane, 1KB/wave dense):
//   Qf[t16][cc][quad][lane16][e8], Kf[kt][half][cc][quad][lane16][e8],
//   Vf[kt][j][quad][lane16][e8]   (per bh, 262144 u16 each; bijective remaps)
template <int EPI, int TM, int TN, int MINW>
__global__ __launch_bounds__(256, MINW) void gemm_kernel(
    const u16* __restrict__ A, const u16* __restrict__ Bt, int K,
    const float* __restrict__ resid, float* __restrict__ outf,
    u16* __restrict__ ob0, u16* __restrict__ ob1, u16* __restrict__ ob2) {
  constexpr int MR  = TM / 32;
  constexpr int NR  = TN / 32;
  constexpr int NAR = TM / 64;
  constexpr int NBR = TN / 64;
  __shared__ __align__(16) u16 As[2][TM * 32];
  __shared__ __align__(16) u16 Bs[2][TN * 32];
  int tid = threadIdx.x;
  int lane = tid & 63, wave = tid >> 6;
  int lane16 = lane & 15, quad = lane >> 4;
  int m0 = blockIdx.y * TM, n0 = blockIdx.x * TN;
  int wm = (wave >> 1) * (TM / 2), wn = (wave & 1) * (TN / 2);

  floatx4 acc[MR][NR];
  #pragma unroll
  for (int i = 0; i < MR; i++)
    #pragma unroll
    for (int j = 0; j < NR; j++) acc[i][j] = (floatx4)(0.0f);

  const u16* agp[NAR]; u16* alp[NAR][2];
  const u16* bgp[NBR]; u16* blp[NBR][2];
  #pragma unroll
  for (int i = 0; i < NAR; i++) {
    int s = i * 256 + tid;
    agp[i] = A + (size_t)(m0 + (s >> 2)) * K + (s & 3) * 8;
    alp[i][0] = &As[0][(i * 256 + wave * 64) * 8];
    alp[i][1] = &As[1][(i * 256 + wave * 64) * 8];
  }
  #pragma unroll
  for (int i = 0; i < NBR; i++) {
    int s = i * 256 + tid;
    bgp[i] = Bt + (size_t)(n0 + (s >> 2)) * K + (s & 3) * 8;
    blp[i][0] = &Bs[0][(i * 256 + wave * 64) * 8];
    blp[i][1] = &Bs[1][(i * 256 + wave * 64) * 8];
  }

  int nk = K >> 5;
  #pragma unroll
  for (int i = 0; i < NAR; i++) glds16(agp[i], alp[i][0]);
  #pragma unroll
  for (int i = 0; i < NBR; i++) glds16(bgp[i], blp[i][0]);

  for (int kt = 0; kt < nk; kt++) {
    __syncthreads();
    int buf = kt & 1;
    if (kt + 1 < nk) {
      int k1 = (kt + 1) * 32;
      #pragma unroll
      for (int i = 0; i < NAR; i++) glds16(agp[i] + k1, alp[i][buf ^ 1]);
      #pragma unroll
      for (int i = 0; i < NBR; i++) glds16(bgp[i] + k1, blp[i][buf ^ 1]);
    }
    short8 af[MR];
    #pragma unroll
    for (int i = 0; i < MR; i++)
      af[i] = *(const short8*)&As[buf][(wm + i * 16 + lane16) * 32 + quad * 8];
    #pragma unroll
    for (int j = 0; j < NR; j++) {
      short8 bfj = *(const short8*)&Bs[buf][(wn + j * 16 + lane16) * 32 + quad * 8];
      #pragma unroll
      for (int i = 0; i < MR; i++)
        acc[i][j] = __builtin_amdgcn_mfma_f32_16x16x32_bf16(af[i], bfj, acc[i][j], 0, 0, 0);
    }
  }

  #pragma unroll
  for (int i = 0; i < MR; i++) {
    #pragma unroll
    for (int j = 0; j < NR; j++) {
      #pragma unroll
      for (int r = 0; r < 4; r++) {
        int m = m0 + wm + i * 16 + quad * 4 + r;
        int n = n0 + wn + j * 16 + lane16;
        float v = acc[i][j][r];
        if (EPI == 0) {
          int bb = m >> 11, t = m & 2047;
          int nn = n & 511, which = n >> 9;
          int h = nn >> 7, d = nn & 127;
          size_t base = (size_t)(bb * NH + h) * 262144;
          if (which == 0) {
            // Qf: t16=t>>4, l16=t&15; cc=d>>5, qd=(d>>3)&3, e=d&7
            int t16 = t >> 4, l16 = t & 15, cc = d >> 5, qd = (d >> 3) & 3, e = d & 7;
            ob0[base + (size_t)((t16 * 16 + cc * 4 + qd) * 128 + l16 * 8 + e)] = f2bf(v * 0.12751743f);
          } else if (which == 1) {
            // Kf: kt=t>>5, hf=(t>>4)&1, l16=t&15; cc=d>>5, qd=(d>>3)&3, e=d&7
            int kt = t >> 5, hf = (t >> 4) & 1, l16 = t & 15, cc = d >> 5, qd = (d >> 3) & 3, e = d & 7;
            ob1[base + (size_t)((kt * 8 + hf * 4 + cc) * 512 + qd * 128 + l16 * 8 + e)] = f2bf(v);
          } else {
            // Vf: kt=t>>5, qv=(t>>3)&3, e=t&7; j=d>>4, l16=d&15
            int kt = t >> 5, qv = (t >> 3) & 3, e = t & 7, j2 = d >> 4, l16 = d & 15;
            ob2[base + (size_t)((kt * 8 + j2) * 512 + qv * 128 + l16 * 8 + e)] = f2bf(v);
          }
        } else if (EPI == 1) {
          size_t idx = (size_t)m * CMOD + n;
          outf[idx] = v + resid[idx];
        } else if (EPI == 2) {
          float ge = 0.5f * v * (1.0f + erff(v * 0.70710678118654752f));
          ob0[(size_t)m * DFF + n] = f2bf(ge);
        } else {
          size_t idx = (size_t)m * CMOD + n;
          outf[idx] = v + resid[idx];
        }
      }
    }
  }
}

// ---------------- flash attention: LDS-free, fragment-blocked coalesced loads ----------------
// R3 was LDS-pipe/barrier-lockstep bound; R4's direct loads were gathers (16 lines/
// load). With Q/K/V pre-blocked by the QKV epilogue, every fragment read is
// lane-contiguous: addr = base(kt,frag) + lane*16B -> one dense 1KB wave transaction,
// L2-resident. No LDS, no barriers, per-wave early exit at causal bound. No setprio
// (R5 A/B: it cost ~6% + 12 VGPR here). Same fragment values + MFMA order as R3
// -> bit-identical output.
__global__ __launch_bounds__(256) void attn_kernel(const u16* __restrict__ qb,
                                                   const u16* __restrict__ kb,
                                                   const u16* __restrict__ vtb,
                                                   u16* __restrict__ po,
                                                   float* __restrict__ pl) {
  int tid = threadIdx.x, wave = tid >> 6, lane = tid & 63;
  int lane16 = lane & 15, quad = lane >> 4;
  int bh = blockIdx.x;
  int cid = 79 - (int)blockIdx.y;  // heavy chunks dispatch first
  int qt, c;
  if (cid < 8)       { qt = cid;                    c = 0; }
  else if (cid < 24) { qt = 8 + ((cid - 8) >> 1);   c = (cid - 8) & 1; }
  else if (cid < 48) { qt = 16 + (cid - 24) / 3;    c = (cid - 24) % 3; }
  else               { qt = 24 + ((cid - 48) >> 2); c = (cid - 48) & 3; }

  int q0w = qt * 64 + wave * 16;
  const u16* Qb = qb  + (size_t)bh * 262144;
  const u16* Kb = kb  + (size_t)bh * 262144;
  const u16* Vb = vtb + (size_t)bh * 262144;

  short8 aq[4];
  #pragma unroll
  for (int cc = 0; cc < 4; cc++)
    aq[cc] = *(const short8*)&Qb[(size_t)(((q0w >> 4) * 16 + cc * 4 + quad) * 128 + lane16 * 8)];

  int ktw   = (q0w >> 5) + 1;                    // causal limit for this wave
  int ktblk = qt * 2 + 2;
  int kt0   = c * 16;
  int kend  = min(min(kt0 + 16, ktblk), ktw);    // >= kt0+1 always (see ledger)

  floatx4 o[8];
  #pragma unroll
  for (int j = 0; j < 8; j++) o[j] = (floatx4)(0.0f);
  floatx4 ol = (floatx4)(0.0f);

  short8 ones;
  #pragma unroll
  for (int e = 0; e < 8; e++) ones[e] = (short)0x3F80;

  int addrA = (lane16 + ((quad & 1) << 5)) << 2;
  int addrB = addrA + 64;
  int q_g = q0w + lane16;

  const u16* kp = Kb + (size_t)kt0 * 4096 + lane * 8;
  const u16* vp = Vb + (size_t)kt0 * 4096 + lane * 8;

  for (int kt = kt0; kt < kend; kt++) {
    // K fragments: kf0 = Kf[kt][0][cc][quad][lane16], kf1 = half 1. Coalesced.
    short8 k0f[4], k1f[4];
    #pragma unroll
    for (int cc = 0; cc < 4; cc++) {
      k0f[cc] = *(const short8*)&kp[cc * 512];
      k1f[cc] = *(const short8*)&kp[(4 + cc) * 512];
    }

    // Swapped QK^T: st[r] = P[q = lane16][k = kt*32 + quad*4 + r (+16 for st1)]
    floatx4 st0 = (floatx4)(0.0f), st1 = (floatx4)(0.0f);
    #pragma unroll
    for (int cc = 0; cc < 4; cc++) {
      st0 = __builtin_amdgcn_mfma_f32_16x16x32_bf16(k0f[cc], aq[cc], st0, 0, 0, 0);
      st1 = __builtin_amdgcn_mfma_f32_16x16x32_bf16(k1f[cc], aq[cc], st1, 0, 0, 0);
    }

    // V fragments issue now; latency hides under exp/pack/bpermute
    short8 vfr[8];
    #pragma unroll
    for (int j = 0; j < 8; j++)
      vfr[j] = *(const short8*)&vp[j * 512];

    int k0b = kt * 32 + quad * 4;
    #pragma unroll
    for (int r = 0; r < 4; r++) {
      float p0 = exp2a(st0[r]);
      float p1 = exp2a(st1[r]);
      if (k0b + r > q_g) p0 = 0.0f;
      if (k0b + r + 16 > q_g) p1 = 0.0f;
      st0[r] = p0; st1[r] = p1;
    }
    uint32_t x0 = __builtin_amdgcn_perm(__float_as_uint(st0[1]), __float_as_uint(st0[0]), 0x07060302u);
    uint32_t x1 = __builtin_amdgcn_perm(__float_as_uint(st0[3]), __float_as_uint(st0[2]), 0x07060302u);
    uint32_t y0 = __builtin_amdgcn_perm(__float_as_uint(st1[1]), __float_as_uint(st1[0]), 0x07060302u);
    uint32_t y1 = __builtin_amdgcn_perm(__float_as_uint(st1[3]), __float_as_uint(st1[2]), 0x07060302u);

    int pAx0 = __builtin_amdgcn_ds_bpermute(addrA, (int)x0);
    int pAx1 = __builtin_amdgcn_ds_bpermute(addrA, (int)x1);
    int pBx0 = __builtin_amdgcn_ds_bpermute(addrB, (int)x0);
    int pBx1 = __builtin_amdgcn_ds_bpermute(addrB, (int)x1);
    int pAy0 = __builtin_amdgcn_ds_bpermute(addrA, (int)y0);
    int pAy1 = __builtin_amdgcn_ds_bpermute(addrA, (int)y1);
    int pBy0 = __builtin_amdgcn_ds_bpermute(addrB, (int)y0);
    int pBy1 = __builtin_amdgcn_ds_bpermute(addrB, (int)y1);

    union { uint32_t u[4]; short8 s; } pf;
    bool hi = quad >= 2;
    pf.u[0] = (uint32_t)(hi ? pAy0 : pAx0);
    pf.u[1] = (uint32_t)(hi ? pAy1 : pAx1);
    pf.u[2] = (uint32_t)(hi ? pBy0 : pBx0);
    pf.u[3] = (uint32_t)(hi ? pBy1 : pBx1);

    #pragma unroll
    for (int j = 0; j < 8; j++)
      o[j] = __builtin_amdgcn_mfma_f32_16x16x32_bf16(pf.s, vfr[j], o[j], 0, 0, 0);
    ol = __builtin_amdgcn_mfma_f32_16x16x32_bf16(pf.s, ones, ol, 0, 0, 0);

    kp += 4096;
    vp += 4096;
  }

  int slot = (bh * 32 + qt) * 4 + c;
  u16* pob = po + (size_t)slot * 8192;
  #pragma unroll
  for (int r = 0; r < 4; r++) {
    int qr = wave * 16 + quad * 4 + r;
    #pragma unroll
    for (int j = 0; j < 8; j++)
      pob[qr * 128 + j * 16 + lane16] = f2bf(o[j][r]);
    if (lane16 == 0) pl[slot * 64 + qr] = ol[r];
  }
}

// ---------------- reduce: VERBATIM (frozen) ----------------
__global__ __launch_bounds__(256) void reduce_kernel(const u16* __restrict__ po,
                                                     const float* __restrict__ pl,
                                                     u16* __restrict__ attn) {
  int bh = blockIdx.x >> 5, qt = blockIdx.x & 31;
  int tid = threadIdx.x;
  int nch = (2 * qt + 17) >> 4;
  int qrow = tid >> 2;
  int d0 = (tid & 3) * 32;
  float acc[32];
  #pragma unroll
  for (int i = 0; i < 32; i++) acc[i] = 0.0f;
  float l = 0.0f;
  int slot0 = (bh * 32 + qt) * 4;
  for (int c = 0; c < nch; c++) {
    int slot = slot0 + c;
    l += pl[slot * 64 + qrow];
    const short8* p = (const short8*)(po + (size_t)slot * 8192 + qrow * 128 + d0);
    #pragma unroll
    for (int v = 0; v < 4; v++) {
      short8 pk = p[v];
      #pragma unroll
      for (int e = 0; e < 8; e++) acc[v * 8 + e] += bf2f((u16)pk[e]);
    }
  }
  float inv = rcpa(l);
  int b = bh >> 2, h = bh & 3, t = qt * 64 + qrow;
  u16* orow = attn + ((size_t)(b * TSEQ + t)) * CMOD + h * HD + d0;
  #pragma unroll
  for (int v = 0; v < 4; v++) {
    short8 ov;
    #pragma unroll
    for (int e = 0; e < 8; e++) ov[e] = (short)f2bf(acc[v * 8 + e] * inv);
    *(short8*)(orow + v * 8) = ov;
  }
}

extern "C" void kernel_launch(void* const* d_in, const int* in_sizes, int n_in,
                              void* d_out, int out_size, void* d_ws, size_t ws_size,
                              hipStream_t stream) {
  const float* x     = (const float*)d_in[0];
  const float* ln1g  = (const float*)d_in[1];
  const float* ln1b  = (const float*)d_in[2];
  const float* wqkv  = (const float*)d_in[3];
  const float* wproj = (const float*)d_in[4];
  const float* ln2g  = (const float*)d_in[5];
  const float* ln2b  = (const float*)d_in[6];
  const float* wff1  = (const float*)d_in[7];
  const float* wff2  = (const float*)d_in[8];
  float* out = (float*)d_out;
  char* ws = (char*)d_ws;

  u16* wt_qkv  = (u16*)(ws);
  u16* wt_proj = (u16*)(ws + 1572864);
  u16* wt_ff1  = (u16*)(ws + 2097152);
  u16* wt_ff2  = (u16*)(ws + 4194304);
  u16* ln_buf  = (u16*)(ws + 6291456);
  u16* q_buf   = (u16*)(ws + 14680064);
  u16* k_buf   = (u16*)(ws + 23068672);
  u16* vt_buf  = (u16*)(ws + 31457280);
  u16* attn    = (u16*)(ws + 39845888);
  float* x2    = (float*)(ws + 48234496);
  u16* h1      = (u16*)(ws + 65011712);
  u16* po      = (u16*)(ws + 48234496);
  float* pl    = (float*)(ws + 81788928);

  dim3 blk(256);
  prep_kernel<<<dim3(5120), blk, 0, stream>>>(x, ln1g, ln1b, wqkv, wproj, wff1, wff2,
                                              ln_buf, wt_qkv, wt_proj, wt_ff1, wt_ff2);

  // QKV: TM=128,TN=64, grid 24x64 = 1536 blocks
  gemm_kernel<0, 128, 64, 6><<<dim3(CQKV / 64, BT / 128), blk, 0, stream>>>(
      ln_buf, wt_qkv, CMOD, nullptr, nullptr, q_buf, k_buf, vt_buf);

  attn_kernel<<<dim3(NBAT * NH, 80), blk, 0, stream>>>(q_buf, k_buf, vt_buf, po, pl);

  reduce_kernel<<<dim3(512), blk, 0, stream>>>(po, pl, attn);

  // proj: TM=128,TN=64, grid 8x64 = 512 blocks
  gemm_kernel<1, 128, 64, 4><<<dim3(CMOD / 64, BT / 128), blk, 0, stream>>>(
      attn, wt_proj, CMOD, x, x2, nullptr, nullptr, nullptr);

  ln_kernel<<<dim3(BT / 4), blk, 0, stream>>>(x2, ln2g, ln2b, ln_buf);

  // FF1: TM=128,TN=64, grid 32x64 = 2048 blocks
  gemm_kernel<2, 128, 64, 6><<<dim3(DFF / 64, BT / 128), blk, 0, stream>>>(
      ln_buf, wt_ff1, CMOD, nullptr, nullptr, h1, nullptr, nullptr);

  // FF2: TM=128,TN=64, grid 8x64 = 512 blocks
  gemm_kernel<3, 128, 64, 4><<<dim3(CMOD / 64, BT / 128), blk, 0, stream>>>(
      h1, wt_ff2, DFF, x2, out, nullptr, nullptr, nullptr);
}